// Round 8
// baseline (186.273 us; speedup 1.0000x reference)
//
#include <hip/hip_runtime.h>
#include <hip/hip_bf16.h>

// NLinear: out[b,f,o] = sum_i x[b,f,i] * w[f,i,o] + bias[f,o]
// B=8192, F=64, I=128, O=128, fp32.
//
// R8 = R7 (G=4 feature-grouping for 2KB-contiguous DRAM access) with the
// launch failure fixed: LDS is EXACTLY 128KB (the m201-proven max) -- bias
// lives in VGPRs as packed bf16 instead of LDS (R7's 133KB silently failed
// to launch -> all-zero output). Also explicit vmcnt(0)+sched_barrier after
// the staging barrier (rule #18: don't let tile-0 converts hoist).

#define NF 64
#define DI 128
#define DO 128
#define G 4
#define FG 16                 // feature groups
#define CHUNKS 16
#define ROWSPB 512            // rows per block
#define BMT 128               // rows per block-tile (8 waves x 16)
#define TILES 4
#define RS (NF * DI)          // 8192 floats

typedef __attribute__((ext_vector_type(8))) short short8;
typedef __attribute__((ext_vector_type(4))) float floatx4;

static __device__ __forceinline__ unsigned short f2bf(float f) {
    union { float f; unsigned u; } v; v.f = f;
    unsigned r = v.u + 0x7fffu + ((v.u >> 16) & 1u);
    return (unsigned short)(r >> 16);
}
static __device__ __forceinline__ float bflo(unsigned u) {   // low bf16 -> f32
    union { unsigned u; float f; } v; v.u = u << 16; return v.f;
}
static __device__ __forceinline__ float bfhi(unsigned u) {   // high bf16 -> f32
    union { unsigned u; float f; } v; v.u = u & 0xffff0000u; return v.f;
}

// 32 batched dwordx4 loads (4 features x 8), offsets fi*512 + kk*128 + h*16.
#define ISSUE32(r, p)                                                     \
    asm volatile(                                                         \
        "global_load_dwordx4 %0, %32, off\n\t"                            \
        "global_load_dwordx4 %1, %32, off offset:16\n\t"                  \
        "global_load_dwordx4 %2, %32, off offset:128\n\t"                 \
        "global_load_dwordx4 %3, %32, off offset:144\n\t"                 \
        "global_load_dwordx4 %4, %32, off offset:256\n\t"                 \
        "global_load_dwordx4 %5, %32, off offset:272\n\t"                 \
        "global_load_dwordx4 %6, %32, off offset:384\n\t"                 \
        "global_load_dwordx4 %7, %32, off offset:400\n\t"                 \
        "global_load_dwordx4 %8, %32, off offset:512\n\t"                 \
        "global_load_dwordx4 %9, %32, off offset:528\n\t"                 \
        "global_load_dwordx4 %10, %32, off offset:640\n\t"                \
        "global_load_dwordx4 %11, %32, off offset:656\n\t"                \
        "global_load_dwordx4 %12, %32, off offset:768\n\t"                \
        "global_load_dwordx4 %13, %32, off offset:784\n\t"                \
        "global_load_dwordx4 %14, %32, off offset:896\n\t"                \
        "global_load_dwordx4 %15, %32, off offset:912\n\t"                \
        "global_load_dwordx4 %16, %32, off offset:1024\n\t"               \
        "global_load_dwordx4 %17, %32, off offset:1040\n\t"               \
        "global_load_dwordx4 %18, %32, off offset:1152\n\t"               \
        "global_load_dwordx4 %19, %32, off offset:1168\n\t"               \
        "global_load_dwordx4 %20, %32, off offset:1280\n\t"               \
        "global_load_dwordx4 %21, %32, off offset:1296\n\t"               \
        "global_load_dwordx4 %22, %32, off offset:1408\n\t"               \
        "global_load_dwordx4 %23, %32, off offset:1424\n\t"               \
        "global_load_dwordx4 %24, %32, off offset:1536\n\t"               \
        "global_load_dwordx4 %25, %32, off offset:1552\n\t"               \
        "global_load_dwordx4 %26, %32, off offset:1664\n\t"               \
        "global_load_dwordx4 %27, %32, off offset:1680\n\t"               \
        "global_load_dwordx4 %28, %32, off offset:1792\n\t"               \
        "global_load_dwordx4 %29, %32, off offset:1808\n\t"               \
        "global_load_dwordx4 %30, %32, off offset:1920\n\t"               \
        "global_load_dwordx4 %31, %32, off offset:1936\n\t"               \
        : "=&v"(r[0]), "=&v"(r[1]), "=&v"(r[2]), "=&v"(r[3]),             \
          "=&v"(r[4]), "=&v"(r[5]), "=&v"(r[6]), "=&v"(r[7]),             \
          "=&v"(r[8]), "=&v"(r[9]), "=&v"(r[10]), "=&v"(r[11]),           \
          "=&v"(r[12]), "=&v"(r[13]), "=&v"(r[14]), "=&v"(r[15]),         \
          "=&v"(r[16]), "=&v"(r[17]), "=&v"(r[18]), "=&v"(r[19]),         \
          "=&v"(r[20]), "=&v"(r[21]), "=&v"(r[22]), "=&v"(r[23]),         \
          "=&v"(r[24]), "=&v"(r[25]), "=&v"(r[26]), "=&v"(r[27]),         \
          "=&v"(r[28]), "=&v"(r[29]), "=&v"(r[30]), "=&v"(r[31])          \
        : "v"(p) : "memory")

__global__ __launch_bounds__(512, 2)
void nlinear_kernel(const float* __restrict__ x,
                    const float* __restrict__ w,
                    const float* __restrict__ bias,
                    float* __restrict__ out) {
    // 4 W^T panels, bf16, swizzled: (o,i) at fi*32768 + o*256 + ((i*2)^((o&15)<<4)).
    // EXACTLY 131072 bytes -- the proven-launchable static LDS size.
    __shared__ unsigned short lds_wt[G * DI * DO];

    int b = blockIdx.x;
    int fg    = b >> 4;            // 0..15
    int chunk = b & 15;            // 0..15
    int g0 = fg * G;

    int tid  = threadIdx.x;
    int lane = tid & 63;
    int wid  = tid >> 6;           // 0..7
    int lrow = lane & 15;
    int kq   = lane >> 4;          // 0..3

    // ---- bias -> VGPRs, packed bf16 (uniform per 16-lane quarter; L2 broadcast) ----
    unsigned bpk[G][8][2];
    {
        const float* bp = bias + (size_t)g0 * DO + kq * 4;
        #pragma unroll
        for (int fi = 0; fi < G; ++fi)
            #pragma unroll
            for (int n = 0; n < 8; ++n) {
                floatx4 v = *(const floatx4*)(bp + fi * DO + n * 16);
                bpk[fi][n][0] = (unsigned)f2bf(v[0]) | ((unsigned)f2bf(v[1]) << 16);
                bpk[fi][n][1] = (unsigned)f2bf(v[2]) | ((unsigned)f2bf(v[3]) << 16);
            }
    }

    size_t row0 = (size_t)chunk * ROWSPB + wid * 16 + lrow;
    const float* xw = x   + row0 * RS + g0 * DI + kq * 8;
    float*       ow = out + row0 * RS + g0 * DO + kq * 4;

    floatx4 raw[32];
    ISSUE32(raw, xw);              // tile 0 flies under W staging

    // ---- stage 4 W^T panels (paired-row b32 packed writes) ----
    #pragma unroll
    for (int fi = 0; fi < G; ++fi) {
        const float* wf = w + (size_t)(g0 + fi) * DI * DO;
        unsigned short* wt = lds_wt + fi * DI * DO;
        #pragma unroll
        for (int it = 0; it < 4; ++it) {
            int id = it * 512 + tid;       // 0..2047
            int o4 = (id & 31) << 2;
            int i  = (id >> 5) * 2;        // even k-row
            floatx4 v0 = *(const floatx4*)(wf + i * DO + o4);
            floatx4 v1 = *(const floatx4*)(wf + (i + 1) * DO + o4);
            #pragma unroll
            for (int j = 0; j < 4; ++j) {
                int o = o4 + j;
                int byte = o * 256 + ((i * 2) ^ ((o & 15) << 4));
                unsigned pk = (unsigned)f2bf(v0[j]) | ((unsigned)f2bf(v1[j]) << 16);
                *(unsigned*)((char*)wt + byte) = pk;
            }
        }
    }
    __syncthreads();
    // rule #18: make tile-0 loads visibly complete before any convert;
    // sched_barrier stops register-only converts hoisting above.
    asm volatile("s_waitcnt vmcnt(0)" ::: "memory");
    __builtin_amdgcn_sched_barrier(0);

    #pragma unroll 1
    for (int t = 0; t < TILES; ++t) {
        const float* xnext = xw + (size_t)(t + 1) * BMT * RS;
        float* op = ow + (size_t)t * BMT * RS;

        #pragma unroll
        for (int fi = 0; fi < G; ++fi) {
            // Ops newer than feature fi's 8 loads are always exactly 32
            // (remaining loads of this tile + 24 stores + prev-tile f3 stores),
            // so vmcnt(32) guarantees fi's loads have landed without draining
            // the next tile's prefetch.
            asm volatile("s_waitcnt vmcnt(32)" ::: "memory");
            __builtin_amdgcn_sched_barrier(0);

            short8 ax[4];
            #pragma unroll
            for (int kk = 0; kk < 4; ++kk) {
                floatx4 v0 = raw[fi * 8 + kk * 2];
                floatx4 v1 = raw[fi * 8 + kk * 2 + 1];
                short8 a;
                a[0] = (short)f2bf(v0[0]); a[1] = (short)f2bf(v0[1]);
                a[2] = (short)f2bf(v0[2]); a[3] = (short)f2bf(v0[3]);
                a[4] = (short)f2bf(v1[0]); a[5] = (short)f2bf(v1[1]);
                a[6] = (short)f2bf(v1[2]); a[7] = (short)f2bf(v1[3]);
                ax[kk] = a;
            }

            if (fi == G - 1 && t < TILES - 1)
                ISSUE32(raw, xnext);       // raw free after last convert

            // acc init = bias (unpack bf16 pairs; VALU is idle, this is free)
            floatx4 acc[8];
            #pragma unroll
            for (int n = 0; n < 8; ++n) {
                acc[n][0] = bflo(bpk[fi][n][0]);
                acc[n][1] = bfhi(bpk[fi][n][0]);
                acc[n][2] = bflo(bpk[fi][n][1]);
                acc[n][3] = bfhi(bpk[fi][n][1]);
            }

            const char* wtb = (const char*)lds_wt + fi * 32768;
            #pragma unroll
            for (int kk = 0; kk < 4; ++kk) {
                int kb = (kk * 64 + kq * 16) ^ (lrow << 4);
                #pragma unroll
                for (int n = 0; n < 8; ++n) {
                    short8 bw = *(const short8*)(wtb + (n * 16 + lrow) * 256 + kb);
                    acc[n] = __builtin_amdgcn_mfma_f32_16x16x32_bf16(
                                 bw, ax[kk], acc[n], 0, 0, 0);
                }
            }

            #pragma unroll
            for (int n = 0; n < 8; ++n)
                *(floatx4*)(op + fi * DO + n * 16) = acc[n];
        }
    }
}

extern "C" void kernel_launch(void* const* d_in, const int* in_sizes, int n_in,
                              void* d_out, int out_size, void* d_ws, size_t ws_size,
                              hipStream_t stream) {
    const float* x    = (const float*)d_in[0];
    const float* wght = (const float*)d_in[1];
    const float* bias = (const float*)d_in[2];
    float* out        = (float*)d_out;

    dim3 grid(FG * CHUNKS);   // 256 blocks, 1 per CU
    dim3 block(512);
    nlinear_kernel<<<grid, block, 0, stream>>>(x, wght, bias, out);
}

// Round 9
// 150.220 us; speedup vs baseline: 1.2400x; 1.2400x over previous
//
#include <hip/hip_runtime.h>
#include <hip/hip_bf16.h>

// NLinear: out[b,f,o] = sum_i x[b,f,i] * w[f,i,o] + bias[f,o]
// B=8192, F=64, I=128, O=128, fp32.
//
// R9 = R8 (G=4 feature-grouping, 2KB-contiguous DRAM access, proven +42% BW)
// with the register catastrophe fixed: R8 pinned raw[32]=128 VGPRs in one asm
// block -> compiler squeezed everything else into AGPRs/scratch (VGPR=128,
// WRITE amplified 264->374MB = scratch traffic). R9 splits each tile into two
// 16-load batches (feature pairs) ping-ponged through ONE raw[16] buffer:
// footprint ~212 VGPR, no spill. All waits are constant vmcnt(16).

#define NF 64
#define DI 128
#define DO 128
#define G 4
#define FG 16                 // feature groups
#define CHUNKS 16
#define ROWSPB 512            // rows per block
#define BMT 128               // rows per block-tile (8 waves x 16)
#define TILES 4
#define RS (NF * DI)          // 8192 floats

typedef __attribute__((ext_vector_type(8))) short short8;
typedef __attribute__((ext_vector_type(4))) float floatx4;

static __device__ __forceinline__ unsigned short f2bf(float f) {
    union { float f; unsigned u; } v; v.f = f;
    unsigned r = v.u + 0x7fffu + ((v.u >> 16) & 1u);
    return (unsigned short)(r >> 16);
}
static __device__ __forceinline__ float bflo(unsigned u) {
    union { unsigned u; float f; } v; v.u = u << 16; return v.f;
}
static __device__ __forceinline__ float bfhi(unsigned u) {
    union { unsigned u; float f; } v; v.u = u & 0xffff0000u; return v.f;
}

// 16 batched dwordx4 loads (2 features x 8), offsets fi*512 + kk*128 + h*16.
#define ISSUE16(r, p)                                                     \
    asm volatile(                                                         \
        "global_load_dwordx4 %0, %16, off\n\t"                            \
        "global_load_dwordx4 %1, %16, off offset:16\n\t"                  \
        "global_load_dwordx4 %2, %16, off offset:128\n\t"                 \
        "global_load_dwordx4 %3, %16, off offset:144\n\t"                 \
        "global_load_dwordx4 %4, %16, off offset:256\n\t"                 \
        "global_load_dwordx4 %5, %16, off offset:272\n\t"                 \
        "global_load_dwordx4 %6, %16, off offset:384\n\t"                 \
        "global_load_dwordx4 %7, %16, off offset:400\n\t"                 \
        "global_load_dwordx4 %8, %16, off offset:512\n\t"                 \
        "global_load_dwordx4 %9, %16, off offset:528\n\t"                 \
        "global_load_dwordx4 %10, %16, off offset:640\n\t"                \
        "global_load_dwordx4 %11, %16, off offset:656\n\t"                \
        "global_load_dwordx4 %12, %16, off offset:768\n\t"                \
        "global_load_dwordx4 %13, %16, off offset:784\n\t"                \
        "global_load_dwordx4 %14, %16, off offset:896\n\t"                \
        "global_load_dwordx4 %15, %16, off offset:912\n\t"                \
        : "=&v"(r[0]), "=&v"(r[1]), "=&v"(r[2]), "=&v"(r[3]),             \
          "=&v"(r[4]), "=&v"(r[5]), "=&v"(r[6]), "=&v"(r[7]),             \
          "=&v"(r[8]), "=&v"(r[9]), "=&v"(r[10]), "=&v"(r[11]),           \
          "=&v"(r[12]), "=&v"(r[13]), "=&v"(r[14]), "=&v"(r[15])          \
        : "v"(p) : "memory")

__global__ __launch_bounds__(512, 2)
void nlinear_kernel(const float* __restrict__ x,
                    const float* __restrict__ w,
                    const float* __restrict__ bias,
                    float* __restrict__ out) {
    // 4 W^T panels, bf16, swizzled: (o,i) at fi*32768 + o*256 + ((i*2)^((o&15)<<4)).
    // EXACTLY 131072 bytes (the proven-launchable max; R7's +2KB failed launch).
    __shared__ unsigned short lds_wt[G * DI * DO];

    int b = blockIdx.x;
    int fg    = b >> 4;            // 0..15
    int chunk = b & 15;            // 0..15 -> XCD = chunk%8
    int g0 = fg * G;

    int tid  = threadIdx.x;
    int lane = tid & 63;
    int wid  = tid >> 6;           // 0..7
    int lrow = lane & 15;
    int kq   = lane >> 4;          // 0..3

    // ---- bias -> packed bf16 VGPRs (64 regs; uniform per quarter, L2 broadcast) ----
    unsigned bpk[G][8][2];
    {
        const float* bp = bias + (size_t)g0 * DO + kq * 4;
        #pragma unroll
        for (int fi = 0; fi < G; ++fi)
            #pragma unroll
            for (int n = 0; n < 8; ++n) {
                floatx4 v = *(const floatx4*)(bp + fi * DO + n * 16);
                bpk[fi][n][0] = (unsigned)f2bf(v[0]) | ((unsigned)f2bf(v[1]) << 16);
                bpk[fi][n][1] = (unsigned)f2bf(v[2]) | ((unsigned)f2bf(v[3]) << 16);
            }
    }

    size_t row0 = (size_t)chunk * ROWSPB + wid * 16 + lrow;
    const float* xw = x   + row0 * RS + g0 * DI + kq * 8;
    float*       ow = out + row0 * RS + g0 * DO + kq * 4;

    floatx4 raw[16];
    ISSUE16(raw, xw);              // tile 0, features 0-1: fly under W staging

    // ---- stage 4 W^T panels (paired-row b32 packed writes) ----
    #pragma unroll
    for (int fi = 0; fi < G; ++fi) {
        const float* wf = w + (size_t)(g0 + fi) * DI * DO;
        unsigned short* wt = lds_wt + fi * DI * DO;
        #pragma unroll
        for (int it = 0; it < 4; ++it) {
            int id = it * 512 + tid;       // 0..2047
            int o4 = (id & 31) << 2;
            int i  = (id >> 5) * 2;        // even k-row
            floatx4 v0 = *(const floatx4*)(wf + i * DO + o4);
            floatx4 v1 = *(const floatx4*)(wf + (i + 1) * DO + o4);
            #pragma unroll
            for (int j = 0; j < 4; ++j) {
                int o = o4 + j;
                int byte = o * 256 + ((i * 2) ^ ((o & 15) << 4));
                unsigned pk = (unsigned)f2bf(v0[j]) | ((unsigned)f2bf(v1[j]) << 16);
                *(unsigned*)((char*)wt + byte) = pk;
            }
        }
    }
    __syncthreads();
    asm volatile("s_waitcnt vmcnt(0)" ::: "memory");   // tile0-f01 loads landed
    __builtin_amdgcn_sched_barrier(0);

    // convert one feature-pair from raw into ax[0..7]
    auto convert2 = [&](short8* ax) {
        #pragma unroll
        for (int q = 0; q < 8; ++q) {      // q = fi*4 + kk
            floatx4 v0 = raw[q * 2], v1 = raw[q * 2 + 1];
            short8 a;
            a[0] = (short)f2bf(v0[0]); a[1] = (short)f2bf(v0[1]);
            a[2] = (short)f2bf(v0[2]); a[3] = (short)f2bf(v0[3]);
            a[4] = (short)f2bf(v1[0]); a[5] = (short)f2bf(v1[1]);
            a[6] = (short)f2bf(v1[2]); a[7] = (short)f2bf(v1[3]);
            ax[q] = a;
        }
    };

    #pragma unroll 1
    for (int t = 0; t < TILES; ++t) {
        const float* xt = xw + (size_t)t * BMT * RS;
        float* op = ow + (size_t)t * BMT * RS;

        short8 ax[8];

        // ===== phase A: features 0,1 =====
        // steady state outstanding: [f01 loads(16), f23 stores of t-1 (16)]
        // -> vmcnt(16) retires the loads. t=0: already drained, no-op.
        asm volatile("s_waitcnt vmcnt(16)" ::: "memory");
        __builtin_amdgcn_sched_barrier(0);
        convert2(ax);
        ISSUE16(raw, xt + 2 * DI);         // features 2-3 of tile t

        #pragma unroll
        for (int fp = 0; fp < 2; ++fp) {   // ff = fp (features 0,1)
            floatx4 acc[8];
            #pragma unroll
            for (int n = 0; n < 8; ++n) {
                acc[n][0] = bflo(bpk[fp][n][0]);
                acc[n][1] = bfhi(bpk[fp][n][0]);
                acc[n][2] = bflo(bpk[fp][n][1]);
                acc[n][3] = bfhi(bpk[fp][n][1]);
            }
            const char* wtb = (const char*)lds_wt + fp * 32768;
            #pragma unroll
            for (int kk = 0; kk < 4; ++kk) {
                int kb = (kk * 64 + kq * 16) ^ (lrow << 4);
                #pragma unroll
                for (int n = 0; n < 8; ++n) {
                    short8 bw = *(const short8*)(wtb + (n * 16 + lrow) * 256 + kb);
                    acc[n] = __builtin_amdgcn_mfma_f32_16x16x32_bf16(
                                 bw, ax[fp * 4 + kk], acc[n], 0, 0, 0);
                }
            }
            #pragma unroll
            for (int n = 0; n < 8; ++n)
                *(floatx4*)(op + fp * DO + n * 16) = acc[n];
        }

        // ===== phase B: features 2,3 =====
        // outstanding: [f23 loads(16), f01 stores(16)] -> vmcnt(16).
        asm volatile("s_waitcnt vmcnt(16)" ::: "memory");
        __builtin_amdgcn_sched_barrier(0);
        convert2(ax);
        if (t < TILES - 1)
            ISSUE16(raw, xt + (size_t)BMT * RS);   // features 0-1 of tile t+1

        #pragma unroll
        for (int fp = 0; fp < 2; ++fp) {   // ff = 2 + fp
            floatx4 acc[8];
            #pragma unroll
            for (int n = 0; n < 8; ++n) {
                acc[n][0] = bflo(bpk[2 + fp][n][0]);
                acc[n][1] = bfhi(bpk[2 + fp][n][0]);
                acc[n][2] = bflo(bpk[2 + fp][n][1]);
                acc[n][3] = bfhi(bpk[2 + fp][n][1]);
            }
            const char* wtb = (const char*)lds_wt + (2 + fp) * 32768;
            #pragma unroll
            for (int kk = 0; kk < 4; ++kk) {
                int kb = (kk * 64 + kq * 16) ^ (lrow << 4);
                #pragma unroll
                for (int n = 0; n < 8; ++n) {
                    short8 bw = *(const short8*)(wtb + (n * 16 + lrow) * 256 + kb);
                    acc[n] = __builtin_amdgcn_mfma_f32_16x16x32_bf16(
                                 bw, ax[fp * 4 + kk], acc[n], 0, 0, 0);
                }
            }
            #pragma unroll
            for (int n = 0; n < 8; ++n)
                *(floatx4*)(op + (2 + fp) * DO + n * 16) = acc[n];
        }
    }
}

extern "C" void kernel_launch(void* const* d_in, const int* in_sizes, int n_in,
                              void* d_out, int out_size, void* d_ws, size_t ws_size,
                              hipStream_t stream) {
    const float* x    = (const float*)d_in[0];
    const float* wght = (const float*)d_in[1];
    const float* bias = (const float*)d_in[2];
    float* out        = (float*)d_out;

    dim3 grid(FG * CHUNKS);   // 256 blocks, 1 per CU
    dim3 block(512);
    nlinear_kernel<<<grid, block, 0, stream>>>(x, wght, bias, out);
}